// Round 3
// baseline (95.344 us; speedup 1.0000x reference)
//
#include <hip/hip_runtime.h>
#include <hip/hip_bf16.h>

// cost[i,j] = 0.5*(|x_i|^2 + |y_j|^2) - x_i . y_j
// B=1, N=M=4096, D=128, fp32 in/out.
//
// bf16 MFMA for the cross term; fp32 norms computed during staging.
// R2: epilogue round-trips the 128x128 fp32 tile through LDS so global stores
// are row-major float4 (512B contiguous per row) instead of the MFMA C/D
// layout's scattered 64B segments. Output write (64 MB) is the roofline:
// ~11 us at 6.3 TB/s.
// R3: fix compile — __builtin_nontemporal_store needs ext_vector_type, not
// HIP_vector_type<float,4>.

#define NN 4096
#define DD 128
#define TILE 128
#define LDK 136  // bf16 LDS row stride (staging)
#define LDC 132  // fp32 LDS row stride (epilogue tile)

typedef __attribute__((ext_vector_type(8))) short short8;   // 8 bf16 (4 VGPRs)
typedef __attribute__((ext_vector_type(4))) float float4v;  // 4 fp32

static __device__ inline unsigned short f2bf(float v) {
    unsigned int u = __float_as_uint(v);
    unsigned int r = (u + 0x7FFFu + ((u >> 16) & 1u)) >> 16;
    return (unsigned short)r;
}

__global__ __launch_bounds__(256, 2)
void cost_kernel(const float* __restrict__ x, const float* __restrict__ y,
                 float* __restrict__ out) {
    // Staging (bf16 As+Bs, 69632 B) and epilogue tile (fp32 Cs, 67584 B) overlap.
    __shared__ __align__(16) unsigned char smem[TILE * LDK * 2 * sizeof(unsigned short)];
    __shared__ float xn[TILE];  // 0.5*|x_row|^2
    __shared__ float yn[TILE];  // 0.5*|y_col|^2

    unsigned short* As = reinterpret_cast<unsigned short*>(smem);
    unsigned short* Bs = As + TILE * LDK;
    float* Cs = reinterpret_cast<float*>(smem);

    const int tid  = threadIdx.x;
    const int brow = blockIdx.y;
    const int bcol = blockIdx.x;

    // ---- stage: fp32 global -> bf16 LDS, fp32 norms via shuffle-reduce ----
    {
        const float4* sx = reinterpret_cast<const float4*>(x + (size_t)brow * TILE * DD);
        const float4* sy = reinterpret_cast<const float4*>(y + (size_t)bcol * TILE * DD);
        for (int it = 0; it < 16; ++it) {
            int idx = it * 256 + tid;
            int row = idx >> 5;   // 32 float4 per row
            int c4  = idx & 31;
            float4 fx = sx[idx];
            float4 fy = sy[idx];

            ushort4 hx, hy;
            hx.x = f2bf(fx.x); hx.y = f2bf(fx.y); hx.z = f2bf(fx.z); hx.w = f2bf(fx.w);
            hy.x = f2bf(fy.x); hy.y = f2bf(fy.y); hy.z = f2bf(fy.z); hy.w = f2bf(fy.w);
            *reinterpret_cast<ushort4*>(&As[row * LDK + c4 * 4]) = hx;
            *reinterpret_cast<ushort4*>(&Bs[row * LDK + c4 * 4]) = hy;

            float ssx = fx.x * fx.x + fx.y * fx.y + fx.z * fx.z + fx.w * fx.w;
            float ssy = fy.x * fy.x + fy.y * fy.y + fy.z * fy.z + fy.w * fy.w;
            for (int off = 16; off; off >>= 1) {
                ssx += __shfl_xor(ssx, off, 64);
                ssy += __shfl_xor(ssy, off, 64);
            }
            if ((tid & 31) == 0) {
                xn[row] = 0.5f * ssx;
                yn[row] = 0.5f * ssy;
            }
        }
    }
    __syncthreads();

    // ---- MFMA: 4 waves, each a 64x64 sub-tile ----
    const int wave = tid >> 6;
    const int lane = tid & 63;
    const int wm = wave >> 1;
    const int wn = wave & 1;
    const int quad = lane >> 4;
    const int l16  = lane & 15;

    float4v acc[4][4] = {};

    for (int kk = 0; kk < 4; ++kk) {
        const int kbase = kk * 32 + quad * 8;
        short8 a[4], b[4];
        for (int mi = 0; mi < 4; ++mi)
            a[mi] = *reinterpret_cast<const short8*>(&As[(wm * 64 + mi * 16 + l16) * LDK + kbase]);
        for (int ni = 0; ni < 4; ++ni)
            b[ni] = *reinterpret_cast<const short8*>(&Bs[(wn * 64 + ni * 16 + l16) * LDK + kbase]);
        for (int mi = 0; mi < 4; ++mi)
            for (int ni = 0; ni < 4; ++ni)
                acc[mi][ni] = __builtin_amdgcn_mfma_f32_16x16x32_bf16(
                    a[mi], b[ni], acc[mi][ni], 0, 0, 0);
    }

    // All waves done reading As/Bs before Cs overwrites them.
    __syncthreads();

    // ---- fold xn + yn - acc into LDS tile (C/D layout: col=l16, row=quad*4+r) ----
    for (int mi = 0; mi < 4; ++mi) {
        const int lrow = wm * 64 + mi * 16 + quad * 4;
        for (int ni = 0; ni < 4; ++ni) {
            const int lcol = wn * 64 + ni * 16 + l16;
            const float ynv = yn[lcol];
            #pragma unroll
            for (int r = 0; r < 4; ++r)
                Cs[(lrow + r) * LDC + lcol] = (xn[lrow + r] + ynv) - acc[mi][ni][r];
        }
    }
    __syncthreads();

    // ---- stream tile out row-major: float4, 512B contiguous per row ----
    {
        float* obase = out + (size_t)(brow * TILE) * NN + (size_t)bcol * TILE;
        for (int it = 0; it < 16; ++it) {
            int idx = it * 256 + tid;
            int row = idx >> 5;
            int c4  = idx & 31;
            float4v v = *reinterpret_cast<const float4v*>(&Cs[row * LDC + c4 * 4]);
            __builtin_nontemporal_store(v, reinterpret_cast<float4v*>(obase + (size_t)row * NN + c4 * 4));
        }
    }
}

extern "C" void kernel_launch(void* const* d_in, const int* in_sizes, int n_in,
                              void* d_out, int out_size, void* d_ws, size_t ws_size,
                              hipStream_t stream) {
    const float* x = (const float*)d_in[0];
    const float* y = (const float*)d_in[1];
    float* out = (float*)d_out;
    dim3 grid(NN / TILE, NN / TILE);  // (32, 32)
    cost_kernel<<<grid, dim3(256), 0, stream>>>(x, y, out);
}